// Round 5
// baseline (864.675 us; speedup 1.0000x reference)
//
#include <hip/hip_runtime.h>
#include <hip/hip_bf16.h>

#define BB 8
#define NN 2048
#define DD 128
#define TI 32     // i-rows per GEMM block (256 threads)
#define HP 132    // padded row stride for 128-wide LDS tiles
#define CH 32     // chunk length
#define NC (NN / CH)   // 64 chunks per batch
#define NO (NC + 1)    // 65 offset rows (incl. grand total)
#define NFIX (BB * NO) // 520 fix blocks inside mid kernel
#define OG 16          // rows per block in out kernel

// ---- INSTRUMENTATION ROUND: per-kernel idempotent repetition ----
// Each kernel is a pure function; repeating its body R times multiplies its
// duration by R (semantics unchanged) so per-kernel durations+counters surface
// in the rocprof top-5 above the 42us harness fills. True t_k = shown / R_k.
#define R1 20
#define R2 25
#define R3 14
#define R4 33
#define R5 20
#define REP_FENCE() asm volatile("" ::: "memory")

__device__ __forceinline__ float relu(float x) { return x > 0.f ? x : 0.f; }

typedef __attribute__((ext_vector_type(8))) __bf16 bf16x8;
typedef __attribute__((ext_vector_type(4))) float f32x4;

// split fp32 -> bf16 hi/lo (bf16x3 trick, fp32-quality accumulation)
__device__ __forceinline__ void cvt2(float x, __bf16& hi, __bf16& lo) {
    hi = (__bf16)x;
    lo = (__bf16)(x - (float)hi);
}

// ---------- Kernel 1: hw = h@W^T (bf16x3 MFMA); E=exp(si), F=exp(sj) ----------
__global__ __launch_bounds__(256) void GraphAttentionalLayer_1168231104632_kernel(
    const float* __restrict__ h,
    const float* __restrict__ W,
    const float* __restrict__ a,
    float* __restrict__ hw,
    float* __restrict__ E,
    float* __restrict__ F)
{
    __shared__ float hw_s[TI][HP];    // 16.9 KB

    const int tid = threadIdx.x;
    const int lane = tid & 63;
    const int w  = tid >> 6;          // wave 0..3
    const int wm = w & 1;             // row half (16 rows)
    const int wn = w >> 1;            // col half (64 cols)
    const int lr = lane & 15;         // row (A) / col (B) within frag
    const int kg = lane >> 4;         // k-group: k = kg*8 + e
    const int b  = blockIdx.x >> 6;
    const int i0 = (blockIdx.x & 63) * TI;

    const int arow = i0 + wm * 16 + lr;
    const float* hrow = h + ((size_t)b * NN + arow) * DD;

#pragma unroll 1
    for (int rep = 0; rep < R1; ++rep) {
        REP_FENCE();
        f32x4 acc[4];
#pragma unroll
        for (int nf = 0; nf < 4; nf++) acc[nf] = (f32x4){0.f, 0.f, 0.f, 0.f};

#pragma unroll
        for (int kc = 0; kc < 4; kc++) {
            const int kb = kc * 32 + kg * 8;
            const float4 av0 = *reinterpret_cast<const float4*>(hrow + kb);
            const float4 av1 = *reinterpret_cast<const float4*>(hrow + kb + 4);
            const float av[8] = {av0.x, av0.y, av0.z, av0.w, av1.x, av1.y, av1.z, av1.w};
            bf16x8 ah, al;
#pragma unroll
            for (int e = 0; e < 8; e++) { __bf16 hi, lo; cvt2(av[e], hi, lo); ah[e] = hi; al[e] = lo; }

#pragma unroll
            for (int nf = 0; nf < 4; nf++) {
                const int wr = wn * 64 + nf * 16 + lr;     // W row = output col
                const float* wrow = W + (size_t)wr * DD + kb;
                const float4 bv0 = *reinterpret_cast<const float4*>(wrow);
                const float4 bv1 = *reinterpret_cast<const float4*>(wrow + 4);
                const float bv[8] = {bv0.x, bv0.y, bv0.z, bv0.w, bv1.x, bv1.y, bv1.z, bv1.w};
                bf16x8 bh, bl;
#pragma unroll
                for (int e = 0; e < 8; e++) { __bf16 hi, lo; cvt2(bv[e], hi, lo); bh[e] = hi; bl[e] = lo; }

                acc[nf] = __builtin_amdgcn_mfma_f32_16x16x32_bf16(ah, bh, acc[nf], 0, 0, 0);
                acc[nf] = __builtin_amdgcn_mfma_f32_16x16x32_bf16(ah, bl, acc[nf], 0, 0, 0);
                acc[nf] = __builtin_amdgcn_mfma_f32_16x16x32_bf16(al, bh, acc[nf], 0, 0, 0);
            }
        }

#pragma unroll
        for (int nf = 0; nf < 4; nf++)
#pragma unroll
            for (int r = 0; r < 4; r++)
                hw_s[wm * 16 + kg * 4 + r][wn * 64 + nf * 16 + lr] = acc[nf][r];
        __syncthreads();

        const int row = tid >> 3;
        const int cb  = (tid & 7) * 4;
        const size_t gbase = ((size_t)b * NN + i0 + row) * DD;
        float pi = 0.f, pj = 0.f;
#pragma unroll
        for (int qq = 0; qq < 4; qq++) {
            const int col = cb + qq * 32;
            const float4 v = *reinterpret_cast<const float4*>(&hw_s[row][col]);
            *reinterpret_cast<float4*>(&hw[gbase + col]) = v;
            const float4 avi = *reinterpret_cast<const float4*>(&a[col]);
            const float4 avj = *reinterpret_cast<const float4*>(&a[DD + col]);
            pi += v.x * avi.x + v.y * avi.y + v.z * avi.z + v.w * avi.w;
            pj += v.x * avj.x + v.y * avj.y + v.z * avj.z + v.w * avj.w;
        }
#pragma unroll
        for (int off = 4; off > 0; off >>= 1) {
            pi += __shfl_down(pi, off, 8);
            pj += __shfl_down(pj, off, 8);
        }
        if ((tid & 7) == 0) {
            const size_t rr = (size_t)b * NN + i0 + row;
            E[rr] = __expf(pi);
            F[rr] = __expf(pj);
        }
        __syncthreads();   // protect hw_s across reps
    }
}

// ---------- Kernel 2: rank-sort, float4 LDS compare loop ----------
__global__ __launch_bounds__(256) void GraphAttentionalLayer_1168231104632_rank(
    const float* __restrict__ F,
    float* __restrict__ Fsorted,
    int* __restrict__ perm)
{
    __shared__ float F_s[NN];
    __shared__ int   part[4][64];

    const int t = threadIdx.x;
    const int b = blockIdx.x >> 5;
    const int j0 = (blockIdx.x & 31) * 64;
    const size_t nb = (size_t)b * NN;

#pragma unroll 1
    for (int rep = 0; rep < R2; ++rep) {
        REP_FENCE();
        for (int q = 0; q < NN / 256; q++)
            F_s[q * 256 + t] = F[nb + q * 256 + t];
        __syncthreads();

        const int tj = t & 63, ts = t >> 6;
        const int j = j0 + tj;
        const float fj = F_s[j];
        const int m0 = ts * (NN / 4);
        int cnt = 0;
        const float4* F4 = reinterpret_cast<const float4*>(&F_s[m0]);
#pragma unroll 8
        for (int mi4 = 0; mi4 < NN / 16; mi4++) {
            const float4 fm4 = F4[mi4];
            const int m = m0 + mi4 * 4;
            cnt += (fm4.x < fj) | ((fm4.x == fj) & (m     < j));
            cnt += (fm4.y < fj) | ((fm4.y == fj) & (m + 1 < j));
            cnt += (fm4.z < fj) | ((fm4.z == fj) & (m + 2 < j));
            cnt += (fm4.w < fj) | ((fm4.w == fj) & (m + 3 < j));
        }
        part[ts][tj] = cnt;
        __syncthreads();
        if (ts == 0) {
            const int r = part[0][tj] + part[1][tj] + part[2][tj] + part[3][tj];
            Fsorted[nb + r] = fj;
            perm[nb + r] = j;
        }
        __syncthreads();   // protect F_s/part across reps
    }
}

// ---------- Kernel 3: chunked prefix scans ----------
__global__ __launch_bounds__(128) void GraphAttentionalLayer_1168231104632_scan(
    const float* __restrict__ hw,
    const float* __restrict__ Fsorted,
    const int* __restrict__ perm,
    float* __restrict__ Q0L, float* __restrict__ Q1L,
    float* __restrict__ C0,  float* __restrict__ C1)
{
    const int t = threadIdx.x;
    const int b = blockIdx.x / NC, c = blockIdx.x % NC;
    const size_t nb = (size_t)b * NN;
    const int m0 = c * CH;

#pragma unroll 1
    for (int rep = 0; rep < R3; ++rep) {
        REP_FENCE();
        int   jv[CH];
        float Fv[CH];
#pragma unroll
        for (int mm = 0; mm < CH; mm++) jv[mm] = perm[nb + m0 + mm];
#pragma unroll
        for (int mm = 0; mm < CH; mm++) Fv[mm] = Fsorted[nb + m0 + mm];

        float hv[CH];
#pragma unroll
        for (int mm = 0; mm < CH; mm++)
            hv[mm] = hw[(nb + jv[mm]) * DD + t];

        float a0 = 0.f, a1 = 0.f;
#pragma unroll
        for (int mm = 0; mm < CH; mm++) {
            const int m = m0 + mm;
            Q0L[(nb + m) * DD + t] = a0;
            Q1L[(nb + m) * DD + t] = a1;
            a0 += hv[mm];
            a1 += Fv[mm] * hv[mm];
        }
        C0[((size_t)b * NC + c) * DD + t] = a0;
        C1[((size_t)b * NC + c) * DD + t] = a1;
    }
}

// ---------- Kernel 4 (mid): fix offsets + parallel LDS search ----------
__global__ __launch_bounds__(256) void GraphAttentionalLayer_1168231104632_mid(
    const float* __restrict__ C0, const float* __restrict__ C1,
    const float* __restrict__ Fsorted, const float* __restrict__ E,
    float* __restrict__ O0, float* __restrict__ O1,
    int* __restrict__ kk,  float* __restrict__ zinv)
{
    __shared__ float fs_s[NN];      // 8 KB
    __shared__ float cf_s[NC];
    __shared__ float of_s[NO];

    const int tid = threadIdx.x;

    if (blockIdx.x < NFIX) {
        const int b = blockIdx.x / NO, c = blockIdx.x % NO;
        const int d = tid & 127;
        const float* C = (tid < 128) ? C0 : C1;
        float*       O = (tid < 128) ? O0 : O1;
#pragma unroll 1
        for (int rep = 0; rep < R4; ++rep) {
            REP_FENCE();
            float o = 0.f;
            int c2 = 0;
            for (; c2 + 16 <= c; c2 += 16) {
                float v[16];
#pragma unroll
                for (int q = 0; q < 16; q++)
                    v[q] = C[((size_t)b * NC + c2 + q) * DD + d];
#pragma unroll
                for (int q = 0; q < 16; q++) o += v[q];
            }
            for (; c2 < c; c2++)
                o += C[((size_t)b * NC + c2) * DD + d];
            O[((size_t)b * NO + c) * DD + d] = o;
        }
        return;
    }

    const int sb = blockIdx.x - NFIX;
    const int b = sb >> 3;
    const int i0 = (sb & 7) * 256;
    const size_t nb = (size_t)b * NN;

#pragma unroll 1
    for (int rep = 0; rep < R4; ++rep) {
        REP_FENCE();
        for (int q = 0; q < NN / 256; q++)
            fs_s[q * 256 + tid] = Fsorted[nb + q * 256 + tid];
        __syncthreads();

        if (tid < NC) {
            float p = 0.f;
            const int m0 = tid * CH;
#pragma unroll
            for (int mm = 0; mm < CH; mm++) p += fs_s[m0 + mm];
            cf_s[tid] = p;
        }
        __syncthreads();
        if (tid < NO) {
            float p = 0.f;
            for (int c2 = 0; c2 < tid; c2++) p += cf_s[c2];
            of_s[tid] = p;
        }
        __syncthreads();

        const int row = (int)nb + i0 + tid;
        const float Ei = E[row];
        const float thr = 1.0f / Ei;
        int lo = 0, hi = NN;
        while (lo < hi) {
            const int mid = (lo + hi) >> 1;
            if (fs_s[mid] < thr) lo = mid + 1; else hi = mid;
        }
        float fpl = 0.f;
        for (int m = (lo >> 5) << 5; m < lo; m++) fpl += fs_s[m];
        const float TF = of_s[NC];
        const float Pk = of_s[lo >> 5] + fpl;
        const float z = Ei * (TF - Pk) + (float)lo;
        kk[row] = lo;
        zinv[row] = 1.0f / z;
        __syncthreads();   // protect fs_s/cf_s/of_s across reps
    }
}

// ---------- Kernel 5: output, 16 rows per 256-thread block ----------
__global__ __launch_bounds__(256) void GraphAttentionalLayer_1168231104632_out(
    const float* __restrict__ Q0L, const float* __restrict__ Q1L,
    const float* __restrict__ O0,  const float* __restrict__ O1,
    const int* __restrict__ kk,    const float* __restrict__ zinv,
    const float* __restrict__ E,   float* __restrict__ out)
{
    const int tid = threadIdx.x;
    const int t  = tid & 127;            // d index
    const int rp = tid >> 7;             // row parity 0/1
    const int r0 = blockIdx.x * OG;      // first row of this block
    const int b  = r0 >> 11;             // batch (constant per block)
    const size_t nb = (size_t)b * NN;
    const float* O0b = O0 + (size_t)b * NO * DD;
    const float* O1b = O1 + (size_t)b * NO * DD;

#pragma unroll 1
    for (int rep = 0; rep < R5; ++rep) {
        REP_FENCE();
        const float T1  = O1b[(size_t)NC * DD + t];   // batch totals
        const float TQ0 = O0b[(size_t)NC * DD + t];

#pragma unroll
        for (int q = 0; q < OG / 2; q++) {
            const int row = r0 + q * 2 + rp;
            const int k = kk[row];           // uniform across the row's 128 threads
            const float Ev = E[row];
            const float zv = zinv[row];

            float num;
            if (k < NN) {
                const int c = k >> 5;
                const float q0 = Q0L[(nb + k) * DD + t] + O0b[(size_t)c * DD + t];
                const float q1 = Q1L[(nb + k) * DD + t] + O1b[(size_t)c * DD + t];
                num = Ev * (T1 - q1) + q0;
            } else {
                num = TQ0;
            }
            out[(size_t)row * DD + t] = relu(num * zv);
        }
    }
}

extern "C" __attribute__((visibility("default")))
void kernel_launch(void* const* d_in, const int* in_sizes, int n_in,
                   void* d_out, int out_size, void* d_ws, size_t ws_size,
                   hipStream_t stream) {
    const float* h = nullptr; const float* W = nullptr; const float* a = nullptr;
    for (int i = 0; i < n_in; i++) {
        if (in_sizes[i] == BB * NN * DD)      h = (const float*)d_in[i];
        else if (in_sizes[i] == DD * DD)      W = (const float*)d_in[i];
        else if (in_sizes[i] == 2 * DD)       a = (const float*)d_in[i];
    }
    if (!h) h = (const float*)d_in[0];
    if (!W) W = (const float*)d_in[1];
    if (!a) a = (const float*)d_in[2];

    float* out = (float*)d_out;
    float* ws = (float*)d_ws;

    float* hw   = ws;                              // 2,097,152
    float* E    = hw + (size_t)BB * NN * DD;       // 16,384
    float* F    = E + BB * NN;                     // 16,384
    float* Fs   = F + BB * NN;                     // 16,384
    float* zinv = Fs + BB * NN;                    // 16,384
    int*   perm = (int*)(zinv + BB * NN);          // 16,384
    int*   kk   = perm + BB * NN;                  // 16,384
    float* Q0L  = (float*)(kk + BB * NN);          // 2,097,152
    float* Q1L  = Q0L + (size_t)BB * NN * DD;      // 2,097,152
    float* C0   = Q1L + (size_t)BB * NN * DD;      // 65,536
    float* C1   = C0 + BB * NC * DD;               // 65,536
    float* O0   = C1 + BB * NC * DD;               // 66,560
    float* O1   = O0 + BB * NO * DD;               // 66,560
    const size_t need = (size_t)((O1 + BB * NO * DD) - ws) * sizeof(float); // ~26.3 MB

    if (ws_size < need || d_ws == nullptr) {
        hipMemsetAsync(d_out, 0x42, (size_t)out_size * sizeof(float), stream);
        return;
    }

    GraphAttentionalLayer_1168231104632_kernel<<<BB * (NN / TI), 256, 0, stream>>>(h, W, a, hw, E, F);
    GraphAttentionalLayer_1168231104632_rank<<<BB * 32, 256, 0, stream>>>(F, Fs, perm);
    GraphAttentionalLayer_1168231104632_scan<<<BB * NC, 128, 0, stream>>>(hw, Fs, perm, Q0L, Q1L, C0, C1);
    GraphAttentionalLayer_1168231104632_mid<<<NFIX + BB * 8, 256, 0, stream>>>(C0, C1, Fs, E, O0, O1, kk, zinv);
    GraphAttentionalLayer_1168231104632_out<<<(BB * NN) / OG, 256, 0, stream>>>(Q0L, Q1L, O0, O1, kk, zinv, E, out);
}

// Round 6
// 99.277 us; speedup vs baseline: 8.7097x; 8.7097x over previous
//
#include <hip/hip_runtime.h>
#include <hip/hip_bf16.h>

#define BB 8
#define NN 2048
#define DD 128
#define TI 32     // i-rows per GEMM block (256 threads)
#define HP 132    // padded row stride for 128-wide LDS tiles
#define CH 32     // chunk length
#define NC (NN / CH)   // 64 chunks per batch
#define NO (NC + 1)    // 65 offset rows (incl. grand total)
#define NFIX (BB * NO) // 520 fix blocks inside mid kernel
#define OG 16          // rows per block in out kernel
#define RB 128         // rank blocks per batch (r5: was 32; 1024 total = 4 blocks/CU)

__device__ __forceinline__ float relu(float x) { return x > 0.f ? x : 0.f; }

typedef __attribute__((ext_vector_type(8))) __bf16 bf16x8;
typedef __attribute__((ext_vector_type(4))) float f32x4;

// split fp32 -> bf16 hi/lo (bf16x3 trick, fp32-quality accumulation)
__device__ __forceinline__ void cvt2(float x, __bf16& hi, __bf16& lo) {
    hi = (__bf16)x;
    lo = (__bf16)(x - (float)hi);
}

// ---------- Kernel 1: hw = h@W^T (bf16x3 MFMA); E=exp(si), F=exp(sj) ----------
// r2-verified MFMA version (absmax 0.00195). t ~= 5us (r5 instrumentation).
__global__ __launch_bounds__(256) void GraphAttentionalLayer_1168231104632_kernel(
    const float* __restrict__ h,
    const float* __restrict__ W,
    const float* __restrict__ a,
    float* __restrict__ hw,
    float* __restrict__ E,
    float* __restrict__ F)
{
    __shared__ float hw_s[TI][HP];    // 16.9 KB

    const int tid = threadIdx.x;
    const int lane = tid & 63;
    const int w  = tid >> 6;          // wave 0..3
    const int wm = w & 1;             // row half (16 rows)
    const int wn = w >> 1;            // col half (64 cols)
    const int lr = lane & 15;         // row (A) / col (B) within frag
    const int kg = lane >> 4;         // k-group: k = kg*8 + e
    const int b  = blockIdx.x >> 6;
    const int i0 = (blockIdx.x & 63) * TI;

    const int arow = i0 + wm * 16 + lr;
    const float* hrow = h + ((size_t)b * NN + arow) * DD;

    f32x4 acc[4];
#pragma unroll
    for (int nf = 0; nf < 4; nf++) acc[nf] = (f32x4){0.f, 0.f, 0.f, 0.f};

#pragma unroll
    for (int kc = 0; kc < 4; kc++) {
        const int kb = kc * 32 + kg * 8;
        const float4 av0 = *reinterpret_cast<const float4*>(hrow + kb);
        const float4 av1 = *reinterpret_cast<const float4*>(hrow + kb + 4);
        const float av[8] = {av0.x, av0.y, av0.z, av0.w, av1.x, av1.y, av1.z, av1.w};
        bf16x8 ah, al;
#pragma unroll
        for (int e = 0; e < 8; e++) { __bf16 hi, lo; cvt2(av[e], hi, lo); ah[e] = hi; al[e] = lo; }

#pragma unroll
        for (int nf = 0; nf < 4; nf++) {
            const int wr = wn * 64 + nf * 16 + lr;     // W row = output col
            const float* wrow = W + (size_t)wr * DD + kb;
            const float4 bv0 = *reinterpret_cast<const float4*>(wrow);
            const float4 bv1 = *reinterpret_cast<const float4*>(wrow + 4);
            const float bv[8] = {bv0.x, bv0.y, bv0.z, bv0.w, bv1.x, bv1.y, bv1.z, bv1.w};
            bf16x8 bh, bl;
#pragma unroll
            for (int e = 0; e < 8; e++) { __bf16 hi, lo; cvt2(bv[e], hi, lo); bh[e] = hi; bl[e] = lo; }

            acc[nf] = __builtin_amdgcn_mfma_f32_16x16x32_bf16(ah, bh, acc[nf], 0, 0, 0);
            acc[nf] = __builtin_amdgcn_mfma_f32_16x16x32_bf16(ah, bl, acc[nf], 0, 0, 0);
            acc[nf] = __builtin_amdgcn_mfma_f32_16x16x32_bf16(al, bh, acc[nf], 0, 0, 0);
        }
    }

    // scatter D-frags to LDS: col = lr, row = kg*4 + r (verified C/D map)
#pragma unroll
    for (int nf = 0; nf < 4; nf++)
#pragma unroll
        for (int r = 0; r < 4; r++)
            hw_s[wm * 16 + kg * 4 + r][wn * 64 + nf * 16 + lr] = acc[nf][r];
    __syncthreads();

    // coalesced hw write + fused E/F epilogue (8 threads per row)
    const int row = tid >> 3;
    const int cb  = (tid & 7) * 4;
    const size_t gbase = ((size_t)b * NN + i0 + row) * DD;
    float pi = 0.f, pj = 0.f;
#pragma unroll
    for (int qq = 0; qq < 4; qq++) {
        const int col = cb + qq * 32;
        const float4 v = *reinterpret_cast<const float4*>(&hw_s[row][col]);
        *reinterpret_cast<float4*>(&hw[gbase + col]) = v;
        const float4 avi = *reinterpret_cast<const float4*>(&a[col]);
        const float4 avj = *reinterpret_cast<const float4*>(&a[DD + col]);
        pi += v.x * avi.x + v.y * avi.y + v.z * avi.z + v.w * avi.w;
        pj += v.x * avj.x + v.y * avj.y + v.z * avj.z + v.w * avj.w;
    }
#pragma unroll
    for (int off = 4; off > 0; off >>= 1) {
        pi += __shfl_down(pi, off, 8);
        pj += __shfl_down(pj, off, 8);
    }
    if ((tid & 7) == 0) {
        const size_t rr = (size_t)b * NN + i0 + row;
        E[rr] = __expf(pi);
        F[rr] = __expf(pj);
    }
}

// ---------- Kernel 2: rank-sort, 1024 blocks (r5 occupancy fix) ----------
// r5 instrumentation: old 256-block version = 15.1us at 11.9% occupancy
// (1 block/CU, 1 wave/SIMD -> latency-bound). New: 4 blocks/CU, 16 waves/CU;
// each block ranks 16 j's with 16 segments of 128 elements per thread.
__global__ __launch_bounds__(256) void GraphAttentionalLayer_1168231104632_rank(
    const float* __restrict__ F,
    float* __restrict__ Fsorted,
    int* __restrict__ perm)
{
    __shared__ float F_s[NN];        // 8 KB
    __shared__ int   part[16][16];   // 1 KB

    const int t = threadIdx.x;
    const int b = blockIdx.x >> 7;           // 128 blocks per batch
    const int j0 = (blockIdx.x & (RB - 1)) * 16;
    const size_t nb = (size_t)b * NN;

    for (int q = 0; q < NN / 256; q++)
        F_s[q * 256 + t] = F[nb + q * 256 + t];
    __syncthreads();

    const int tj = t & 15, ts = t >> 4;      // 16 j's x 16 segments
    const int j = j0 + tj;
    const float fj = F_s[j];
    const int m0 = ts * (NN / 16);           // 128-element segment
    int cnt = 0;
    // 16 lanes per ts-group share each LDS address -> broadcast
    const float4* F4 = reinterpret_cast<const float4*>(&F_s[m0]);
#pragma unroll 8
    for (int mi4 = 0; mi4 < NN / 64; mi4++) {   // 32 float4 reads
        const float4 fm4 = F4[mi4];
        const int m = m0 + mi4 * 4;
        cnt += (fm4.x < fj) | ((fm4.x == fj) & (m     < j));
        cnt += (fm4.y < fj) | ((fm4.y == fj) & (m + 1 < j));
        cnt += (fm4.z < fj) | ((fm4.z == fj) & (m + 2 < j));
        cnt += (fm4.w < fj) | ((fm4.w == fj) & (m + 3 < j));
    }
    part[ts][tj] = cnt;
    __syncthreads();
    if (ts == 0) {
        int r = 0;
#pragma unroll
        for (int s = 0; s < 16; s++) r += part[s][tj];
        Fsorted[nb + r] = fj;
        perm[nb + r] = j;
    }
}

// ---------- Kernel 3: chunked prefix scans (r13 verbatim) ----------
__global__ __launch_bounds__(128) void GraphAttentionalLayer_1168231104632_scan(
    const float* __restrict__ hw,
    const float* __restrict__ Fsorted,
    const int* __restrict__ perm,
    float* __restrict__ Q0L, float* __restrict__ Q1L,
    float* __restrict__ C0,  float* __restrict__ C1)
{
    const int t = threadIdx.x;
    const int b = blockIdx.x / NC, c = blockIdx.x % NC;
    const size_t nb = (size_t)b * NN;
    const int m0 = c * CH;

    int   jv[CH];
    float Fv[CH];
#pragma unroll
    for (int mm = 0; mm < CH; mm++) jv[mm] = perm[nb + m0 + mm];
#pragma unroll
    for (int mm = 0; mm < CH; mm++) Fv[mm] = Fsorted[nb + m0 + mm];

    float hv[CH];
#pragma unroll
    for (int mm = 0; mm < CH; mm++)
        hv[mm] = hw[(nb + jv[mm]) * DD + t];

    float a0 = 0.f, a1 = 0.f;
#pragma unroll
    for (int mm = 0; mm < CH; mm++) {
        const int m = m0 + mm;
        Q0L[(nb + m) * DD + t] = a0;
        Q1L[(nb + m) * DD + t] = a1;
        a0 += hv[mm];
        a1 += Fv[mm] * hv[mm];
    }
    C0[((size_t)b * NC + c) * DD + t] = a0;
    C1[((size_t)b * NC + c) * DD + t] = a1;
}

// ---------- Kernel 4 (mid): fix offsets + parallel LDS search (r13 verbatim) ----------
__global__ __launch_bounds__(256) void GraphAttentionalLayer_1168231104632_mid(
    const float* __restrict__ C0, const float* __restrict__ C1,
    const float* __restrict__ Fsorted, const float* __restrict__ E,
    float* __restrict__ O0, float* __restrict__ O1,
    int* __restrict__ kk,  float* __restrict__ zinv)
{
    __shared__ float fs_s[NN];      // 8 KB
    __shared__ float cf_s[NC];
    __shared__ float of_s[NO];

    const int tid = threadIdx.x;

    if (blockIdx.x < NFIX) {
        const int b = blockIdx.x / NO, c = blockIdx.x % NO;
        const int d = tid & 127;
        const float* C = (tid < 128) ? C0 : C1;
        float*       O = (tid < 128) ? O0 : O1;
        float o = 0.f;
        int c2 = 0;
        for (; c2 + 16 <= c; c2 += 16) {
            float v[16];
#pragma unroll
            for (int q = 0; q < 16; q++)
                v[q] = C[((size_t)b * NC + c2 + q) * DD + d];
#pragma unroll
            for (int q = 0; q < 16; q++) o += v[q];
        }
        for (; c2 < c; c2++)
            o += C[((size_t)b * NC + c2) * DD + d];
        O[((size_t)b * NO + c) * DD + d] = o;
        return;
    }

    const int sb = blockIdx.x - NFIX;
    const int b = sb >> 3;
    const int i0 = (sb & 7) * 256;
    const size_t nb = (size_t)b * NN;

    for (int q = 0; q < NN / 256; q++)
        fs_s[q * 256 + tid] = Fsorted[nb + q * 256 + tid];
    __syncthreads();

    if (tid < NC) {
        float p = 0.f;
        const int m0 = tid * CH;
#pragma unroll
        for (int mm = 0; mm < CH; mm++) p += fs_s[m0 + mm];
        cf_s[tid] = p;
    }
    __syncthreads();
    if (tid < NO) {
        float p = 0.f;
        for (int c2 = 0; c2 < tid; c2++) p += cf_s[c2];
        of_s[tid] = p;
    }
    __syncthreads();

    const int row = (int)nb + i0 + tid;
    const float Ei = E[row];
    const float thr = 1.0f / Ei;
    int lo = 0, hi = NN;
    while (lo < hi) {
        const int mid = (lo + hi) >> 1;
        if (fs_s[mid] < thr) lo = mid + 1; else hi = mid;
    }
    float fpl = 0.f;
    for (int m = (lo >> 5) << 5; m < lo; m++) fpl += fs_s[m];
    const float TF = of_s[NC];
    const float Pk = of_s[lo >> 5] + fpl;
    const float z = Ei * (TF - Pk) + (float)lo;
    kk[row] = lo;
    zinv[row] = 1.0f / z;
}

// ---------- Kernel 5: output, 16 rows per 256-thread block (r4) ----------
__global__ __launch_bounds__(256) void GraphAttentionalLayer_1168231104632_out(
    const float* __restrict__ Q0L, const float* __restrict__ Q1L,
    const float* __restrict__ O0,  const float* __restrict__ O1,
    const int* __restrict__ kk,    const float* __restrict__ zinv,
    const float* __restrict__ E,   float* __restrict__ out)
{
    const int tid = threadIdx.x;
    const int t  = tid & 127;            // d index
    const int rp = tid >> 7;             // row parity 0/1
    const int r0 = blockIdx.x * OG;      // first row of this block
    const int b  = r0 >> 11;             // batch (constant per block)
    const size_t nb = (size_t)b * NN;
    const float* O0b = O0 + (size_t)b * NO * DD;
    const float* O1b = O1 + (size_t)b * NO * DD;

    const float T1  = O1b[(size_t)NC * DD + t];   // batch totals
    const float TQ0 = O0b[(size_t)NC * DD + t];

#pragma unroll
    for (int q = 0; q < OG / 2; q++) {
        const int row = r0 + q * 2 + rp;
        const int k = kk[row];           // uniform across the row's 128 threads
        const float Ev = E[row];
        const float zv = zinv[row];

        float num;
        if (k < NN) {
            const int c = k >> 5;
            const float q0 = Q0L[(nb + k) * DD + t] + O0b[(size_t)c * DD + t];
            const float q1 = Q1L[(nb + k) * DD + t] + O1b[(size_t)c * DD + t];
            num = Ev * (T1 - q1) + q0;
        } else {
            num = TQ0;
        }
        out[(size_t)row * DD + t] = relu(num * zv);
    }
}

extern "C" __attribute__((visibility("default")))
void kernel_launch(void* const* d_in, const int* in_sizes, int n_in,
                   void* d_out, int out_size, void* d_ws, size_t ws_size,
                   hipStream_t stream) {
    const float* h = nullptr; const float* W = nullptr; const float* a = nullptr;
    for (int i = 0; i < n_in; i++) {
        if (in_sizes[i] == BB * NN * DD)      h = (const float*)d_in[i];
        else if (in_sizes[i] == DD * DD)      W = (const float*)d_in[i];
        else if (in_sizes[i] == 2 * DD)       a = (const float*)d_in[i];
    }
    if (!h) h = (const float*)d_in[0];
    if (!W) W = (const float*)d_in[1];
    if (!a) a = (const float*)d_in[2];

    float* out = (float*)d_out;
    float* ws = (float*)d_ws;

    float* hw   = ws;                              // 2,097,152
    float* E    = hw + (size_t)BB * NN * DD;       // 16,384
    float* F    = E + BB * NN;                     // 16,384
    float* Fs   = F + BB * NN;                     // 16,384
    float* zinv = Fs + BB * NN;                    // 16,384
    int*   perm = (int*)(zinv + BB * NN);          // 16,384
    int*   kk   = perm + BB * NN;                  // 16,384
    float* Q0L  = (float*)(kk + BB * NN);          // 2,097,152
    float* Q1L  = Q0L + (size_t)BB * NN * DD;      // 2,097,152
    float* C0   = Q1L + (size_t)BB * NN * DD;      // 65,536
    float* C1   = C0 + BB * NC * DD;               // 65,536
    float* O0   = C1 + BB * NC * DD;               // 66,560
    float* O1   = O0 + BB * NO * DD;               // 66,560
    const size_t need = (size_t)((O1 + BB * NO * DD) - ws) * sizeof(float); // ~26.3 MB

    if (ws_size < need || d_ws == nullptr) {
        hipMemsetAsync(d_out, 0x42, (size_t)out_size * sizeof(float), stream);
        return;
    }

    GraphAttentionalLayer_1168231104632_kernel<<<BB * (NN / TI), 256, 0, stream>>>(h, W, a, hw, E, F);
    GraphAttentionalLayer_1168231104632_rank<<<BB * RB, 256, 0, stream>>>(F, Fs, perm);
    GraphAttentionalLayer_1168231104632_scan<<<BB * NC, 128, 0, stream>>>(hw, Fs, perm, Q0L, Q1L, C0, C1);
    GraphAttentionalLayer_1168231104632_mid<<<NFIX + BB * 8, 256, 0, stream>>>(C0, C1, Fs, E, O0, O1, kk, zinv);
    GraphAttentionalLayer_1168231104632_out<<<(BB * NN) / OG, 256, 0, stream>>>(Q0L, Q1L, O0, O1, kk, zinv, E, out);
}